// Round 3
// baseline (1573.852 us; speedup 1.0000x reference)
//
#include <hip/hip_runtime.h>
#include <hip/hip_fp16.h>

// GCN 3-layer forward. R8 = src-partitioned pulls:
//  - k_csr sorts each row's srcs by src-partition (4 x ~4MB of table = one XCD L2)
//  - per layer: 3 accumulate passes (k_acc<P>) + 1 finalize pass (k_fin*),
//    each pass touches only one 4MB table slice -> gathers become L2 hits
//  - acc = global fp32 (nontemporal), segments pad-to-2, int2 srcS reads
// Baseline R7: 999 us, k_pull1 FETCH 840MB (75% gather L2-miss confirmed).

typedef unsigned int uint;
typedef unsigned short ushort;

#define NB 512            // dst buckets (dst >> 10), 1024 nodes each
#define BKN 1024
#define KEYS 4096         // BKN * 4 partitions
#define PT_THREADS 512
#define PT_TILE 8192      // 16 edges per thread
#define SLAB_SLACK 8192   // per-bucket srcS slack (max pads 4096 + align)
#define STAGE_CAP 36096   // LDS stage entries (mean 34816, ~7 sigma headroom)

__device__ __forceinline__ uint padOf(uint s) { return min(3u, s >> 17); }

// ---- bucket histogram ----
__global__ void k_hist(const int* __restrict__ dst, int E, uint* __restrict__ bcnt) {
    __shared__ uint h[NB];
    int t = threadIdx.x;
    for (int i = t; i < NB; i += 256) h[i] = 0;
    __syncthreads();
    for (long long e = (long long)blockIdx.x * 256 + t; e < E; e += (long long)gridDim.x * 256)
        atomicAdd(&h[((uint)dst[e]) >> 10], 1u);
    __syncthreads();
    for (int i = t; i < NB; i += 256) if (h[i]) atomicAdd(&bcnt[i], h[i]);
}

// single block, NB threads: exclusive scan -> bbase[0..NB], init gcur
__global__ void k_scan_buckets(const uint* __restrict__ bcnt, uint* __restrict__ bbase,
                               uint* __restrict__ gcur) {
    __shared__ uint s[NB];
    int t = threadIdx.x;
    uint v = bcnt[t];
    s[t] = v;
    __syncthreads();
    for (int off = 1; off < NB; off <<= 1) {
        uint x = (t >= off) ? s[t - off] : 0u;
        __syncthreads();
        s[t] += x;
        __syncthreads();
    }
    uint ex = s[t] - v;
    bbase[t] = ex;
    gcur[t] = ex;
    if (t == NB - 1) bbase[NB] = s[t];
}

// ---- LDS-staged partition: edges -> bucketed (packed src | dstLocal<<19) ----
__global__ __launch_bounds__(PT_THREADS) void k_part(const int* __restrict__ src,
                                                     const int* __restrict__ dst, int E,
                                                     uint* __restrict__ gcur,
                                                     uint* __restrict__ bucketed) {
    __shared__ uint stage[PT_TILE];
    __shared__ ushort sbuck[PT_TILE];
    __shared__ uint hist[NB], lofs[NB], base[NB];
    int t = threadIdx.x;
    long long start = (long long)blockIdx.x * PT_TILE;
    int cnt = (int)min((long long)PT_TILE, (long long)E - start);

    hist[t] = 0;
    __syncthreads();
    uint myb[16], myr[16], mys[16];
#pragma unroll
    for (int k = 0; k < 16; ++k) {
        int idx = t + k * PT_THREADS;
        if (idx < cnt) {
            uint d = (uint)dst[start + idx];
            uint s = (uint)src[start + idx];
            uint b = d >> 10;
            myb[k] = b;
            mys[k] = s | ((d & 1023u) << 19);
            myr[k] = atomicAdd(&hist[b], 1u);
        }
    }
    __syncthreads();
    uint v = hist[t];
    lofs[t] = v;
    __syncthreads();
    for (int off = 1; off < NB; off <<= 1) {
        uint x = (t >= off) ? lofs[t - off] : 0u;
        __syncthreads();
        lofs[t] += x;
        __syncthreads();
    }
    uint ex = lofs[t] - v;
    __syncthreads();
    lofs[t] = ex;
    base[t] = atomicAdd(&gcur[t], v);
    __syncthreads();
#pragma unroll
    for (int k = 0; k < 16; ++k) {
        int idx = t + k * PT_THREADS;
        if (idx < cnt) {
            uint pos = lofs[myb[k]] + myr[k];
            stage[pos] = mys[k];
            sbuck[pos] = (ushort)myb[k];
        }
    }
    __syncthreads();
#pragma unroll
    for (int k = 0; k < 16; ++k) {
        int idx = t + k * PT_THREADS;
        if (idx < cnt) {
            uint b = sbuck[idx];
            bucketed[base[b] + ((uint)idx - lofs[b])] = stage[idx];
        }
    }
}

// ---- per-bucket CSR build: counting sort keyed by (dstLocal*4 + srcPart) ----
// rows stored partition-major, each (node,part) segment padded to even length
// (pad slots = sentinel N -> zero row). rowp2 = [rowStart, paddedRowEnd).
__global__ __launch_bounds__(512) void k_csr(const uint* __restrict__ bucketed,
                                             const uint* __restrict__ bbase,
                                             uint2* __restrict__ rowp2,
                                             ushort4* __restrict__ cnt4,
                                             float* __restrict__ dis,
                                             int* __restrict__ srcS, int N) {
    __shared__ uint c[KEYS];               // counts -> cursors (reused)
    __shared__ uint tsum[512];
    __shared__ __align__(16) int stage[STAGE_CAP];
    int b = blockIdx.x, t = threadIdx.x;
    uint beg = bbase[b], end = bbase[b + 1];
    for (int i = t; i < KEYS; i += 512) c[i] = 0;
    __syncthreads();
    for (uint e = beg + t; e < end; e += 512) {
        uint v = bucketed[e];
        uint key = ((v >> 19) << 2) | padOf(v & 0x7ffffu);
        atomicAdd(&c[key], 1u);
    }
    __syncthreads();
    // thread t owns keys 8t..8t+7 = nodes 2t,2t+1 x 4 partitions
    uint cnt[8], pad[8], psum = 0;
#pragma unroll
    for (int k = 0; k < 8; ++k) {
        cnt[k] = c[t * 8 + k];
        pad[k] = (cnt[k] + 1u) & ~1u;
        psum += pad[k];
    }
    tsum[t] = psum;
    __syncthreads();
    for (int off = 1; off < 512; off <<= 1) {
        uint x = (t >= off) ? tsum[t - off] : 0u;
        __syncthreads();
        tsum[t] += x;
        __syncthreads();
    }
    uint tot = tsum[511];
    uint kb[8];
    {
        uint run = tsum[t] - psum;
#pragma unroll
        for (int k = 0; k < 8; ++k) { kb[k] = run; run += pad[k]; }
    }
    uint slab = ((beg + 3u) & ~3u) + (uint)b * SLAB_SLACK;   // 16B-aligned slab
    int node0 = b * BKN + 2 * t;
    if (node0 < N) {
        rowp2[node0] = make_uint2(slab + kb[0], slab + kb[4]);
        cnt4[node0] = make_ushort4((ushort)cnt[0], (ushort)cnt[1],
                                   (ushort)cnt[2], (ushort)cnt[3]);
        dis[node0] = rsqrtf((float)(cnt[0] + cnt[1] + cnt[2] + cnt[3] + 1u));
    }
    if (node0 + 1 < N) {
        rowp2[node0 + 1] = make_uint2(slab + kb[4], slab + tsum[t]);
        cnt4[node0 + 1] = make_ushort4((ushort)cnt[4], (ushort)cnt[5],
                                       (ushort)cnt[6], (ushort)cnt[7]);
        dis[node0 + 1] = rsqrtf((float)(cnt[4] + cnt[5] + cnt[6] + cnt[7] + 1u));
    }
    // cursors (reuse c) + sentinel pads at fixed final slots
#pragma unroll
    for (int k = 0; k < 8; ++k) {
        c[t * 8 + k] = kb[k];
        if (cnt[k] & 1u) {
            uint idx = kb[k] + cnt[k];
            if (idx < (uint)STAGE_CAP) stage[idx] = N;
            else srcS[slab + idx] = N;          // ~never (spill)
        }
    }
    __syncthreads();
    // fill (LDS cursors, LDS stage)
    for (uint e = beg + t; e < end; e += 512) {
        uint v = bucketed[e];
        uint s = v & 0x7ffffu;
        uint key = ((v >> 19) << 2) | padOf(s);
        uint idx = atomicAdd(&c[key], 1u);
        if (idx < (uint)STAGE_CAP) stage[idx] = (int)s;
        else srcS[slab + idx] = (int)s;         // ~never (spill)
    }
    __syncthreads();
    // sequential dwordx4 writeout + scalar tail
    uint capped = min(tot, (uint)STAGE_CAP);
    uint cap4 = capped & ~3u;
    for (uint i = t * 4; i < cap4; i += 512 * 4)
        *(int4*)(srcS + slab + i) = *(const int4*)(stage + i);
    if (t < (int)(capped & 3u)) srcS[slab + cap4 + t] = stage[cap4 + t];
}

// ---- layer-1: A'[i,0:15] = (x[i,:]@W1) * dis[i] -> fp16, A'[i,15]=0 ----
__global__ void k_lin_first(const float* __restrict__ x, const float* __restrict__ W,
                            const float* __restrict__ dis, __half* __restrict__ A, int N) {
    int i = blockIdx.x * blockDim.x + threadIdx.x;
    if (i >= N) return;
    float in[15];
#pragma unroll
    for (int j = 0; j < 15; ++j) in[j] = x[i * 15 + j];
    float di = dis[i];
#pragma unroll
    for (int o = 0; o < 15; ++o) {
        float acc = 0.f;
#pragma unroll
        for (int j = 0; j < 15; ++j) acc = fmaf(in[j], W[j * 15 + o], acc);
        A[i * 16 + o] = __float2half(acc * di);
    }
    A[i * 16 + 15] = __float2half(0.f);
}

// ---- accumulate pass P (P=0 initializes acc with the self term) ----
template <int P>
__global__ void k_acc(const __half* __restrict__ tab, const int* __restrict__ srcS,
                      const uint2* __restrict__ rowp2, const ushort4* __restrict__ cnt4,
                      float* __restrict__ acc, int N) {
    int tid = blockIdx.x * blockDim.x + threadIdx.x;
    int node = tid >> 4;
    int j = tid & 15;
    if (node >= N) return;
    ushort4 c4 = cnt4[node];
    uint2 rp = rowp2[node];
    uint beg = rp.x;
    if (P > 0) beg += ((uint)c4.x + 1u) & ~1u;
    if (P > 1) beg += ((uint)c4.y + 1u) & ~1u;
    if (P > 2) beg += ((uint)c4.z + 1u) & ~1u;
    uint len = (P == 0) ? (uint)c4.x : (P == 1) ? (uint)c4.y
             : (P == 2) ? (uint)c4.z : (uint)c4.w;
    if (P != 0 && len == 0) return;             // nothing to add
    uint end2 = beg + ((len + 1u) & ~1u);
    float a;
    if (P == 0) a = __half2float(tab[node * 16 + j]);   // self term (pre-scaled)
    else a = __builtin_nontemporal_load(&acc[node * 16 + j]);
    for (uint e = beg; e < end2; e += 2) {
        unsigned long long w =
            __builtin_nontemporal_load((const unsigned long long*)(srcS + e));
        int s0 = (int)(uint)(w & 0xffffffffull);
        int s1 = (int)(uint)(w >> 32);
        a += __half2float(tab[s0 * 16 + j]) + __half2float(tab[s1 * 16 + j]);
    }
    __builtin_nontemporal_store(a, &acc[node * 16 + j]);
}

// ---- finalize layer 1: last partition + relu(dis*Sum + b1) @ W2 -> fp16 B' ----
__global__ void k_fin1(const __half* __restrict__ tab, const int* __restrict__ srcS,
                       const uint2* __restrict__ rowp2, const ushort4* __restrict__ cnt4,
                       const float* __restrict__ acc, const float* __restrict__ dis,
                       const float* __restrict__ W2, const float* __restrict__ b1,
                       __half* __restrict__ Bp, int N) {
    __shared__ float v[16 * 16];
    int tid = blockIdx.x * blockDim.x + threadIdx.x;
    int node = tid >> 4;
    int j = tid & 15;
    int local = threadIdx.x >> 4;
    bool valid = node < N;
    float di = 0.f;
    if (valid) {
        ushort4 c4 = cnt4[node];
        uint2 rp = rowp2[node];
        uint beg = rp.x + (((uint)c4.x + 1u) & ~1u) + (((uint)c4.y + 1u) & ~1u)
                 + (((uint)c4.z + 1u) & ~1u);
        uint end2 = rp.y;                       // padded row end
        float a = __builtin_nontemporal_load(&acc[node * 16 + j]);
        for (uint e = beg; e < end2; e += 2) {
            unsigned long long w =
                __builtin_nontemporal_load((const unsigned long long*)(srcS + e));
            int s0 = (int)(uint)(w & 0xffffffffull);
            int s1 = (int)(uint)(w >> 32);
            a += __half2float(tab[s0 * 16 + j]) + __half2float(tab[s1 * 16 + j]);
        }
        di = dis[node];
        float val = (j < 15) ? (a * di + b1[j]) : 0.f;
        v[local * 16 + j] = val > 0.f ? val : 0.f;
    } else {
        v[local * 16 + j] = 0.f;
    }
    __syncthreads();
    if (valid) {
        float o = 0.f;
        if (j < 15) {
#pragma unroll
            for (int k = 0; k < 15; ++k) o = fmaf(v[local * 16 + k], W2[k * 15 + j], o);
        }
        Bp[node * 16 + j] = __float2half((j < 15 ? o : 0.f) * di);
    }
}

// ---- finalize layer 2: last partition + relu(dis*Sum + b2) @ W3 -> fp16 C' ----
__global__ void k_fin2(const __half* __restrict__ tab, const int* __restrict__ srcS,
                       const uint2* __restrict__ rowp2, const ushort4* __restrict__ cnt4,
                       const float* __restrict__ acc, const float* __restrict__ dis,
                       const float* __restrict__ W3, const float* __restrict__ b2,
                       __half* __restrict__ Cp, int N) {
    __shared__ float v[16 * 16];
    int tid = blockIdx.x * blockDim.x + threadIdx.x;
    int node = tid >> 4;
    int j = tid & 15;
    int local = threadIdx.x >> 4;
    bool valid = node < N;
    float di = 0.f;
    if (valid) {
        ushort4 c4 = cnt4[node];
        uint2 rp = rowp2[node];
        uint beg = rp.x + (((uint)c4.x + 1u) & ~1u) + (((uint)c4.y + 1u) & ~1u)
                 + (((uint)c4.z + 1u) & ~1u);
        uint end2 = rp.y;
        float a = __builtin_nontemporal_load(&acc[node * 16 + j]);
        for (uint e = beg; e < end2; e += 2) {
            unsigned long long w =
                __builtin_nontemporal_load((const unsigned long long*)(srcS + e));
            int s0 = (int)(uint)(w & 0xffffffffull);
            int s1 = (int)(uint)(w >> 32);
            a += __half2float(tab[s0 * 16 + j]) + __half2float(tab[s1 * 16 + j]);
        }
        di = dis[node];
        float val = (j < 15) ? (a * di + b2[j]) : 0.f;
        v[local * 16 + j] = val > 0.f ? val : 0.f;
    } else {
        v[local * 16 + j] = 0.f;
    }
    __syncthreads();
    if (valid && j < 4) {
        float o = 0.f;
#pragma unroll
        for (int k = 0; k < 15; ++k) o = fmaf(v[local * 16 + k], W3[k * 4 + j], o);
        Cp[node * 4 + j] = __float2half(o * di);
    }
}

// ---- pull 3: fp16 C' (4MB, L2-resident) -> out fp32; full padded row ----
__global__ void k_pull3(const __half* __restrict__ Cp, const int* __restrict__ srcS,
                        const uint2* __restrict__ rowp2, const float* __restrict__ dis,
                        const float* __restrict__ b3, float* __restrict__ out, int N) {
    int tid = blockIdx.x * blockDim.x + threadIdx.x;
    int node = tid >> 2;
    int j = tid & 3;
    if (node >= N) return;
    float acc = __half2float(Cp[node * 4 + j]);
    uint2 rp = rowp2[node];
    for (uint e = rp.x; e < rp.y; e += 2) {     // interior pads hit zero row N
        unsigned long long w =
            __builtin_nontemporal_load((const unsigned long long*)(srcS + e));
        int s0 = (int)(uint)(w & 0xffffffffull);
        int s1 = (int)(uint)(w >> 32);
        acc += __half2float(Cp[s0 * 4 + j]) + __half2float(Cp[s1 * 4 + j]);
    }
    out[(size_t)node * 4 + j] = acc * dis[node] + b3[j];
}

extern "C" void kernel_launch(void* const* d_in, const int* in_sizes, int n_in,
                              void* d_out, int out_size, void* d_ws, size_t ws_size,
                              hipStream_t stream) {
    const float* x  = (const float*)d_in[0];
    const int*   ei = (const int*)d_in[1];
    const float* W1 = (const float*)d_in[3];
    const float* b1 = (const float*)d_in[4];
    const float* W2 = (const float*)d_in[5];
    const float* b2 = (const float*)d_in[6];
    const float* W3 = (const float*)d_in[7];
    const float* b3 = (const float*)d_in[8];
    float* out = (float*)d_out;

    const int N = in_sizes[0] / 15;
    const int E = in_sizes[1] / 2;
    const int* src = ei;
    const int* dst = ei + E;
    const int NBr = (N + BKN - 1) / BKN;   // live buckets (489)

    char* ws = (char*)d_ws;
    auto align = [](size_t v) { return (v + 255) & ~(size_t)255; };
    size_t off = 0;
    uint2* rowp2 = (uint2*)(ws + off); off += align((size_t)N * 8);
    float* dis   = (float*)(ws + off); off += align((size_t)N * 4);
    ushort4* cnt4 = (ushort4*)(ws + off); off += align((size_t)N * 8);
    uint* bcnt   = (uint*)(ws + off); off += align((size_t)NB * 4);
    uint* bbase  = (uint*)(ws + off); off += align((size_t)(NB + 1) * 4);
    uint* gcur   = (uint*)(ws + off); off += align((size_t)NB * 4);
    int*  srcS   = (int*)(ws + off);  off += align(((size_t)E + (size_t)NB * SLAB_SLACK + 64) * 4);
    // slabY: bucketed (64MB) dead after k_csr, overlaid by B' + C' + acc
    char* slabY = ws + off;
    uint*   bucketed = (uint*)slabY;
    __half* Bp = (__half*)slabY;
    __half* Cp = (__half*)(slabY + align((size_t)(N + 1) * 16 * 2));
    float*  acc = (float*)(slabY + align((size_t)(N + 1) * 16 * 2)
                                 + align((size_t)(N + 1) * 4 * 2));
    off += align(max((size_t)E * 4,
                     align((size_t)(N + 1) * 16 * 2) + align((size_t)(N + 1) * 4 * 2)
                       + (size_t)N * 16 * 4));
    __half* Ap = (__half*)(ws + off);  // (N+1) x 16 fp16

    const int nTiles = (E + PT_TILE - 1) / PT_TILE;
    const int gN16 = (int)(((long long)N * 16 + 255) / 256);
    const int gN4  = (int)(((long long)N * 4 + 255) / 256);
    const int nbN  = (N + 255) / 256;

    // CSR build (partition-ordered rows)
    hipMemsetAsync(bcnt, 0, (size_t)NB * 4, stream);
    k_hist<<<2048, 256, 0, stream>>>(dst, E, bcnt);
    k_scan_buckets<<<1, NB, 0, stream>>>(bcnt, bbase, gcur);
    k_part<<<nTiles, PT_THREADS, 0, stream>>>(src, dst, E, gcur, bucketed);
    k_csr<<<NBr, 512, 0, stream>>>(bucketed, bbase, rowp2, cnt4, dis, srcS, N);
    // bucketed dead -> slabY becomes B'/C'/acc

    k_lin_first<<<nbN, 256, 0, stream>>>(x, W1, dis, Ap, N);
    // sentinel zero-rows (row N)
    hipMemsetAsync(Ap + (size_t)N * 16, 0, 16 * 2, stream);
    hipMemsetAsync(Bp + (size_t)N * 16, 0, 16 * 2, stream);
    hipMemsetAsync(Cp + (size_t)N * 4, 0, 4 * 2, stream);

    // layer 1: 4 partition passes over A' (each slice ~4MB -> L2-resident)
    k_acc<0><<<gN16, 256, 0, stream>>>(Ap, srcS, rowp2, cnt4, acc, N);
    k_acc<1><<<gN16, 256, 0, stream>>>(Ap, srcS, rowp2, cnt4, acc, N);
    k_acc<2><<<gN16, 256, 0, stream>>>(Ap, srcS, rowp2, cnt4, acc, N);
    k_fin1<<<gN16, 256, 0, stream>>>(Ap, srcS, rowp2, cnt4, acc, dis, W2, b1, Bp, N);

    // layer 2: same over B'
    k_acc<0><<<gN16, 256, 0, stream>>>(Bp, srcS, rowp2, cnt4, acc, N);
    k_acc<1><<<gN16, 256, 0, stream>>>(Bp, srcS, rowp2, cnt4, acc, N);
    k_acc<2><<<gN16, 256, 0, stream>>>(Bp, srcS, rowp2, cnt4, acc, N);
    k_fin2<<<gN16, 256, 0, stream>>>(Bp, srcS, rowp2, cnt4, acc, dis, W3, b2, Cp, N);

    k_pull3<<<gN4, 256, 0, stream>>>(Cp, srcS, rowp2, dis, b3, out, N);
}